// Round 1
// baseline (378.954 us; speedup 1.0000x reference)
//
#include <hip/hip_runtime.h>
#include <hip/hip_cooperative_groups.h>
#include <math.h>

namespace cg = cooperative_groups;

// Problem constants
#define BATCH   64
#define SAMP    32
#define SIGLEN  19530            // sum_{k=1..6} 5^k
#define NROWS   (BATCH * SAMP)   // 2048
#define NF2     (SIGLEN / 2)     // 9765 float2 per row
#define NBISECT 40               // fp32 bisection fixed point after ~30 iters == 100 iters
#define CHB     39               // ceil(NF2/256) output chunks per batch
#define NCHUNK  (BATCH * CHB)    // 2496
#define MAXBLK  1024             // cooperative grid: 4 blocks/CU * 256 CUs

// Level boundaries (element index): {0,5,30,155,780,3905,19530}

// Cross-iteration state lives in module globals, not d_ws.
__device__ float g_pw[NROWS * 6];   // per-row weights (1/SAMP folded in)
__device__ int   g_done[BATCH];     // rows-completed counter per batch

__device__ __forceinline__ int level0(int l) {
    return (l >= 5) + (l >= 30) + (l >= 155) + (l >= 780) + (l >= 3905);
}

// ---------------------------------------------------------------------------
// Phase 1: block-wide reduction of row r -> 6 per-level sums of x^2,
// bisection for the dilatation root, publish weights + release done-flag.
// ---------------------------------------------------------------------------
__device__ __forceinline__ void phase1_row(const float* __restrict__ x, int r, int t,
                                           float (*red)[6]) {
    const float* __restrict__ row = x + (size_t)r * SIGLEN;
    float a1 = 0.f, a2 = 0.f, a3 = 0.f, a4 = 0.f, a5 = 0.f, a6 = 0.f;

    // Levels 1..4: [0,155) static per-thread, [155,780) strided. 4% of bytes.
    if (t < 5)            { float v = row[t]; a1 += v * v; }
    else if (t < 30)      { float v = row[t]; a2 += v * v; }
    else if (t < 155)     { float v = row[t]; a3 += v * v; }
    for (int l = 155 + t; l < 780; l += 256) { float v = row[l]; a4 += v * v; }

    // Levels 5+6: [780,19530) = 18750 elems, float4 body.
    // Row base elem r*19530 % 4 == 2*(r&1): odd rows need a 2-elem head,
    // even rows a 2-elem tail, body is exactly 4687 aligned float4 either way.
    const int head = (r & 1) ? 2 : 0;
    if (head) { if (t == 0)  { float v0 = row[780],   v1 = row[781];   a5 += v0*v0 + v1*v1; } }
    else      { if (t == 32) { float v0 = row[19528], v1 = row[19529]; a6 += v0*v0 + v1*v1; } }

    const float4* __restrict__ p4 = (const float4*)(row + 780 + head);
    const int lb = 780 + head;
    #pragma unroll 4
    for (int q = t; q < 4687; q += 256) {
        const float4 v = p4[q];
        const int l = lb + 4 * q;                     // row-local elem index of v.x
        const float s = v.x*v.x + v.y*v.y + v.z*v.z + v.w*v.w;
        if (l >= 3905)      a6 += s;                  // pure level 6 (vast majority)
        else if (l <= 3901) a5 += s;                  // pure level 5
        else {                                        // the single straddling float4
            ((l     >= 3905) ? a6 : a5) += v.x * v.x;
            ((l + 1 >= 3905) ? a6 : a5) += v.y * v.y;
            ((l + 2 >= 3905) ? a6 : a5) += v.z * v.z;
            ((l + 3 >= 3905) ? a6 : a5) += v.w * v.w;
        }
    }

    // 64-lane butterfly, then cross-wave via LDS
    #pragma unroll
    for (int off = 32; off > 0; off >>= 1) {
        a1 += __shfl_xor(a1, off); a2 += __shfl_xor(a2, off);
        a3 += __shfl_xor(a3, off); a4 += __shfl_xor(a4, off);
        a5 += __shfl_xor(a5, off); a6 += __shfl_xor(a6, off);
    }
    const int wave = t >> 6, lane = t & 63;
    if (lane == 0) {
        red[wave][0] = a1; red[wave][1] = a2; red[wave][2] = a3;
        red[wave][3] = a4; red[wave][4] = a5; red[wave][5] = a6;
    }
    __syncthreads();

    if (t == 0) {
        float s1 = 0.f, s2 = 0.f, s3 = 0.f, s4 = 0.f, s5 = 0.f, s6 = 0.f;
        #pragma unroll
        for (int w = 0; w < 4; ++w) {
            s1 += red[w][0]; s2 += red[w][1]; s3 += red[w][2];
            s4 += red[w][3]; s5 += red[w][4]; s6 += red[w][5];
        }
        const float total = s1 + s2 + s3 + s4 + s5 + s6;
        const float nq  = 1.0f + total;
        // phi with C=4, a=1: x<=4 -> x ; else 8 - 16/x
        const float phi = (nq > 4.0f) ? (8.0f - 16.0f / nq) : nq;
        const float c0  = 1.0f - phi;
        const bool  fin = isfinite(c0) && isfinite(total);

        float lo = 0.0f, hi = 2.0f;
        #pragma unroll 4
        for (int i = 0; i < NBISECT; ++i) {
            const float mid = 0.5f * (lo + hi);
            const float u = mid * mid;
            const float pv = ((((((s6*u + s5)*u + s4)*u + s3)*u + s2)*u + s1)*u) + c0;
            const bool neg = pv < 0.0f;               // NaN -> false (matches jnp.where)
            lo = neg ? mid : lo;
            hi = neg ? hi : mid;
        }
        float root = 0.5f * (lo + hi);
        if (!fin) root = 0.0f;
        root = fminf(root, 1.0f);

        const float inv = 1.0f / SAMP;
        float w1 = root, w2 = w1*root, w3 = w2*root, w4 = w3*root, w5 = w4*root, w6 = w5*root;
        float* dst = g_pw + (size_t)r * 6;
        // agent-scope stores so cross-XCD readers see them (per-XCD L2 non-coherent)
        __hip_atomic_store(dst + 0, w1 * inv, __ATOMIC_RELAXED, __HIP_MEMORY_SCOPE_AGENT);
        __hip_atomic_store(dst + 1, w2 * inv, __ATOMIC_RELAXED, __HIP_MEMORY_SCOPE_AGENT);
        __hip_atomic_store(dst + 2, w3 * inv, __ATOMIC_RELAXED, __HIP_MEMORY_SCOPE_AGENT);
        __hip_atomic_store(dst + 3, w4 * inv, __ATOMIC_RELAXED, __HIP_MEMORY_SCOPE_AGENT);
        __hip_atomic_store(dst + 4, w5 * inv, __ATOMIC_RELAXED, __HIP_MEMORY_SCOPE_AGENT);
        __hip_atomic_store(dst + 5, w6 * inv, __ATOMIC_RELAXED, __HIP_MEMORY_SCOPE_AGENT);
        __hip_atomic_fetch_add(&g_done[r >> 5], 1, __ATOMIC_RELEASE, __HIP_MEMORY_SCOPE_AGENT);
    }
    __syncthreads();   // protect red[] before next row reuses it
}

// ---------------------------------------------------------------------------
// Phase 2: one 256-float2 chunk of out[b,:] = sum_s x[b,s,:]*w[b,s,lev].
// spin=true (cooperative path) waits on the per-batch done flag.
// ---------------------------------------------------------------------------
__device__ __forceinline__ void phase2_chunk(const float* __restrict__ x,
                                             float* __restrict__ out,
                                             int c, int t, float* wsh, bool spin) {
    const int b  = c / CHB;
    const int jc = c - b * CHB;

    if (spin && t == 0) {
        while (__hip_atomic_load(&g_done[b], __ATOMIC_ACQUIRE, __HIP_MEMORY_SCOPE_AGENT) < SAMP)
            __builtin_amdgcn_s_sleep(8);
    }
    __syncthreads();                      // also protects wsh[] reuse across chunks
    if (t < SAMP * 6)
        wsh[t] = __hip_atomic_load(&g_pw[(size_t)b * (SAMP * 6) + t],
                                   __ATOMIC_RELAXED, __HIP_MEMORY_SCOPE_AGENT);
    __syncthreads();

    const int j = jc * 256 + t;           // float2 index within row
    if (j < NF2) {
        const int l0 = 2 * j;
        const int levA = level0(l0);
        const int levB = level0(l0 + 1);
        const float2* __restrict__ x2p = (const float2*)x;
        const unsigned base = (unsigned)b * (SAMP * NF2) + (unsigned)j;

        float acc0 = 0.f, acc1 = 0.f;
        if (levA == levB) {
            #pragma unroll
            for (int s = 0; s < SAMP; ++s) {
                const float  ws = wsh[s * 6 + levA];
                const float2 v  = x2p[base + (unsigned)s * NF2];
                acc0 += v.x * ws; acc1 += v.y * ws;
            }
        } else {                          // 3 straddling threads per row
            #pragma unroll
            for (int s = 0; s < SAMP; ++s) {
                const float2 v = x2p[base + (unsigned)s * NF2];
                acc0 += v.x * wsh[s * 6 + levA];
                acc1 += v.y * wsh[s * 6 + levB];
            }
        }
        float2 rv; rv.x = acc0; rv.y = acc1;
        ((float2*)out)[(unsigned)b * NF2 + (unsigned)j] = rv;
    }
}

// ---------------------------------------------------------------------------
// Fused persistent cooperative kernel: phase 2 of batch b overlaps phase 1 of
// later batches via the done-flag pipeline (co-residency guaranteed by
// cooperative launch -> spin is deadlock-free).
// ---------------------------------------------------------------------------
__global__ __launch_bounds__(256, 4) void es_fused_persistent(
        const float* __restrict__ x, float* __restrict__ out) {
    __shared__ float red[4][6];
    __shared__ float wsh[SAMP * 6];
    const int blk = blockIdx.x, nblk = gridDim.x, t = threadIdx.x;

    if (blk == 0 && t < BATCH)
        __hip_atomic_store(&g_done[t], 0, __ATOMIC_RELAXED, __HIP_MEMORY_SCOPE_AGENT);
    cg::this_grid().sync();               // done[] zeroed before any increments

    for (int r = blk; r < NROWS; r += nblk)
        phase1_row(x, r, t, red);
    for (int c = blk; c < NCHUNK; c += nblk)
        phase2_chunk(x, out, c, t, wsh, true);
}

// Fallback pair (classic path) in case cooperative launch is rejected.
__global__ __launch_bounds__(256) void es_phase1_kernel(const float* __restrict__ x) {
    __shared__ float red[4][6];
    phase1_row(x, blockIdx.x, threadIdx.x, red);
}
__global__ __launch_bounds__(256) void es_phase2_kernel(const float* __restrict__ x,
                                                        float* __restrict__ out) {
    __shared__ float wsh[SAMP * 6];
    phase2_chunk(x, out, blockIdx.x, threadIdx.x, wsh, false);
}

extern "C" void kernel_launch(void* const* d_in, const int* in_sizes, int n_in,
                              void* d_out, int out_size, void* d_ws, size_t ws_size,
                              hipStream_t stream) {
    const float* x = (const float*)d_in[0];   // [64,32,19530] fp32
    float* out = (float*)d_out;               // [64,19530] fp32
    (void)d_ws; (void)ws_size;                // workspace no longer used

    static int nblk = -1;
    if (nblk < 0) {
        int mb = 0;
        hipError_t e = hipOccupancyMaxActiveBlocksPerMultiprocessor(
            &mb, (const void*)es_fused_persistent, 256, 0);
        if (e != hipSuccess || mb < 1) mb = 0;
        long cap = (long)mb * 256;            // 256 CUs on MI355X
        nblk = (int)(cap > MAXBLK ? MAXBLK : cap);   // 0 => classic fallback
    }

    if (nblk > 0) {
        void* args[] = { (void*)&x, (void*)&out };
        if (hipLaunchCooperativeKernel((const void*)es_fused_persistent,
                                       dim3(nblk), dim3(256), args, 0, stream) == hipSuccess)
            return;
        nblk = 0;                             // remember failure, use classic path
    }
    es_phase1_kernel<<<NROWS, 256, 0, stream>>>(x);
    es_phase2_kernel<<<NCHUNK, 256, 0, stream>>>(x, out);
}

// Round 2
// 254.991 us; speedup vs baseline: 1.4861x; 1.4861x over previous
//
#include <hip/hip_runtime.h>
#include <math.h>

// Problem constants
#define BATCH   64
#define SAMP    32
#define SIGLEN  19530            // sum_{k=1..6} 5^k
#define NROWS   (BATCH * SAMP)   // 2048
#define NF2     (SIGLEN / 2)     // 9765 float2 per row
#define NBISECT 40               // fp32 bisection on [0,2] is a fixed point after ~30
                                 // iters (mid rounds to an endpoint) -> identical to 100
#define CHB     39               // ceil(NF2/256) chunks per batch row

// Level boundaries (element index): level k occupies [LB[k-1], LB[k])
// LB = {0, 5, 30, 155, 780, 3905, 19530}

// Per-row weights (1/SAMP folded in). Module global, fully rewritten every
// iteration by phase 1 -> no stale-data hazard, no d_ws dependency.
__device__ float g_pw[NROWS * 6];

__device__ __forceinline__ int level0(int l) {
    return (l >= 5) + (l >= 30) + (l >= 155) + (l >= 780) + (l >= 3905);
}

// ---------------------------------------------------------------------------
// Phase 1: one block per (b,s) row. Block-wide reduction -> 6 per-level sums
// of x^2, bisection for the dilatation root, write w[m] = root^(m+1)/SAMP.
// float4 main body (96% of bytes at 16 B/lane).
// ---------------------------------------------------------------------------
__global__ __launch_bounds__(256) void es_phase1_kernel(const float* __restrict__ x) {
    const int r = blockIdx.x;                 // 0..2047
    const int t = threadIdx.x;
    const float* __restrict__ row = x + (size_t)r * SIGLEN;

    float a1 = 0.f, a2 = 0.f, a3 = 0.f, a4 = 0.f, a5 = 0.f, a6 = 0.f;

    // Levels 1..4: [0,155) static per-thread, [155,780) strided. 4% of bytes.
    if (t < 5)            { float v = row[t]; a1 += v * v; }
    else if (t < 30)      { float v = row[t]; a2 += v * v; }
    else if (t < 155)     { float v = row[t]; a3 += v * v; }
    for (int l = 155 + t; l < 780; l += 256) { float v = row[l]; a4 += v * v; }

    // Levels 5+6: [780,19530) = 18750 elems, float4 body.
    // Row base elem r*19530 % 4 == 2*(r&1): odd rows take a 2-elem head,
    // even rows a 2-elem tail; body is exactly 4687 aligned float4 either way.
    const int head = (r & 1) ? 2 : 0;
    if (head) { if (t == 0)  { float v0 = row[780],   v1 = row[781];   a5 += v0*v0 + v1*v1; } }
    else      { if (t == 32) { float v0 = row[19528], v1 = row[19529]; a6 += v0*v0 + v1*v1; } }

    const float4* __restrict__ p4 = (const float4*)(row + 780 + head);
    const int lb = 780 + head;
    #pragma unroll 4
    for (int q = t; q < 4687; q += 256) {
        const float4 v = p4[q];
        const int l = lb + 4 * q;                     // row-local elem index of v.x
        const float s = v.x*v.x + v.y*v.y + v.z*v.z + v.w*v.w;
        if (l >= 3905)      a6 += s;                  // pure level 6 (vast majority)
        else if (l <= 3901) a5 += s;                  // pure level 5
        else {                                        // the single straddling float4
            ((l     >= 3905) ? a6 : a5) += v.x * v.x;
            ((l + 1 >= 3905) ? a6 : a5) += v.y * v.y;
            ((l + 2 >= 3905) ? a6 : a5) += v.z * v.z;
            ((l + 3 >= 3905) ? a6 : a5) += v.w * v.w;
        }
    }

    // 64-lane butterfly, then cross-wave via LDS
    #pragma unroll
    for (int off = 32; off > 0; off >>= 1) {
        a1 += __shfl_xor(a1, off); a2 += __shfl_xor(a2, off);
        a3 += __shfl_xor(a3, off); a4 += __shfl_xor(a4, off);
        a5 += __shfl_xor(a5, off); a6 += __shfl_xor(a6, off);
    }
    __shared__ float red[4][6];
    const int wave = t >> 6, lane = t & 63;
    if (lane == 0) {
        red[wave][0] = a1; red[wave][1] = a2; red[wave][2] = a3;
        red[wave][3] = a4; red[wave][4] = a5; red[wave][5] = a6;
    }
    __syncthreads();

    if (t == 0) {
        float s1 = 0.f, s2 = 0.f, s3 = 0.f, s4 = 0.f, s5 = 0.f, s6 = 0.f;
        #pragma unroll
        for (int w = 0; w < 4; ++w) {
            s1 += red[w][0]; s2 += red[w][1]; s3 += red[w][2];
            s4 += red[w][3]; s5 += red[w][4]; s6 += red[w][5];
        }
        const float total = s1 + s2 + s3 + s4 + s5 + s6;
        const float nq  = 1.0f + total;
        // phi with C=4, a=1: x<=4 -> x ; else 4 + 16*(1/4 - 1/x) = 8 - 16/x
        const float phi = (nq > 4.0f) ? (8.0f - 16.0f / nq) : nq;
        const float c0  = 1.0f - phi;
        const bool  fin = isfinite(c0) && isfinite(total);

        float lo = 0.0f, hi = 2.0f;
        #pragma unroll 4
        for (int i = 0; i < NBISECT; ++i) {
            const float mid = 0.5f * (lo + hi);
            const float u = mid * mid;
            // poly(u) = c0 + s1 u + ... + s6 u^6 (Horner)
            const float pv = ((((((s6*u + s5)*u + s4)*u + s3)*u + s2)*u + s1)*u) + c0;
            const bool neg = pv < 0.0f;               // NaN -> false (matches jnp.where)
            lo = neg ? mid : lo;
            hi = neg ? hi : mid;
        }
        float root = 0.5f * (lo + hi);
        if (!fin) root = 0.0f;
        root = fminf(root, 1.0f);

        const float inv = 1.0f / SAMP;
        float w1 = root, w2 = w1*root, w3 = w2*root, w4 = w3*root, w5 = w4*root, w6 = w5*root;
        float* dst = g_pw + (size_t)r * 6;
        dst[0] = w1 * inv; dst[1] = w2 * inv; dst[2] = w3 * inv;
        dst[3] = w4 * inv; dst[4] = w5 * inv; dst[5] = w6 * inv;
    }
}

// ---------------------------------------------------------------------------
// Phase 2: out[b,l] = sum_s x[b,s,l] * w[b,s][level(l)]  (1/32 pre-folded).
// float2 over l. Grid: (CHB, BATCH), block 256. Input is L3-resident
// (phase 1 just streamed it; 160 MB < 256 MB Infinity Cache).
// Kernel boundary (same stream) orders g_pw writes -> reads; no atomics.
// ---------------------------------------------------------------------------
__global__ __launch_bounds__(256) void es_phase2_kernel(const float* __restrict__ x,
                                                        float* __restrict__ out) {
    const int b = blockIdx.y;
    const int t = threadIdx.x;

    __shared__ float wsh[SAMP * 6];   // [s*6 + lev]
    if (t < SAMP * 6) wsh[t] = g_pw[(size_t)b * (SAMP * 6) + t];
    __syncthreads();

    const int j = blockIdx.x * 256 + t;      // float2 index within row
    if (j >= NF2) return;

    const int l0 = 2 * j;
    const int levA = level0(l0);
    const int levB = level0(l0 + 1);

    const float2* __restrict__ x2p = (const float2*)x;
    const unsigned base = (unsigned)b * (SAMP * NF2) + (unsigned)j;

    float acc0 = 0.f, acc1 = 0.f;
    if (levA == levB) {
        #pragma unroll
        for (int s = 0; s < SAMP; ++s) {
            const float  ws = wsh[s * 6 + levA];     // single broadcast LDS read
            const float2 v  = x2p[base + (unsigned)s * NF2];
            acc0 += v.x * ws;
            acc1 += v.y * ws;
        }
    } else {                                         // 3 straddling threads per row
        #pragma unroll
        for (int s = 0; s < SAMP; ++s) {
            const float2 v = x2p[base + (unsigned)s * NF2];
            acc0 += v.x * wsh[s * 6 + levA];
            acc1 += v.y * wsh[s * 6 + levB];
        }
    }

    float2 rv; rv.x = acc0; rv.y = acc1;
    ((float2*)out)[(unsigned)b * NF2 + (unsigned)j] = rv;
}

extern "C" void kernel_launch(void* const* d_in, const int* in_sizes, int n_in,
                              void* d_out, int out_size, void* d_ws, size_t ws_size,
                              hipStream_t stream) {
    const float* x = (const float*)d_in[0];   // [64,32,19530] fp32
    float* out = (float*)d_out;               // [64,19530] fp32
    (void)d_ws; (void)ws_size;                // workspace unused

    es_phase1_kernel<<<NROWS, 256, 0, stream>>>(x);
    dim3 gridB(CHB, BATCH);
    es_phase2_kernel<<<gridB, 256, 0, stream>>>(x, out);
}